// Round 1
// baseline (68386.438 us; speedup 1.0000x reference)
//
#include <hip/hip_runtime.h>
#include <cstdint>
#include <cstddef>

#define H   1024
#define V   32000
#define L   2048
#define G4  4096      // 4*H
#define NB  256       // blocks
#define NT  1024      // threads per block (16 waves of 64)
#define RPB (V / NB)  // 125 FC rows per block

// ---------------------------------------------------------------------------
// Wave (64-lane) sum reduction
// ---------------------------------------------------------------------------
__device__ __forceinline__ float wave_reduce_sum(float v) {
    #pragma unroll
    for (int off = 32; off > 0; off >>= 1) v += __shfl_down(v, off);
    return v;
}

__device__ __forceinline__ float sigmoidf_(float x) {
    return 1.0f / (1.0f + expf(-x));
}

// ---------------------------------------------------------------------------
// Init kernel: v0 = w_hh0 @ h0_init + b_ih0 + b_hh0 (4096 rows)
//              u1 = w_hh1 @ h1_init + b_ih1 + b_hh1 (4096 rows)
//              c0 = ctx[0], c1 = ctx[1], h1g = ctx[1], keys <- y[0]
// ---------------------------------------------------------------------------
__global__ __launch_bounds__(NT) void init_kernel(
    const int* __restrict__ y, const float* __restrict__ ctx,
    const float* __restrict__ w_hh0, const float* __restrict__ b_ih0,
    const float* __restrict__ b_hh0,
    const float* __restrict__ w_hh1, const float* __restrict__ b_ih1,
    const float* __restrict__ b_hh1,
    float* __restrict__ v0, float* __restrict__ u1,
    float* __restrict__ c0, float* __restrict__ c1,
    float* __restrict__ h1g, unsigned long long* __restrict__ keys)
{
    __shared__ float h0s[H];
    __shared__ float h1s[H];
    const int b = blockIdx.x, t = threadIdx.x;
    h0s[t] = ctx[t];
    h1s[t] = ctx[H + t];
    __syncthreads();

    const int wave = t >> 6, lane = t & 63;
    // 32 row-dots per block: units 0..15 -> v0 rows, 16..31 -> u1 rows
    for (int unit = wave; unit < 32; unit += 16) {
        const bool isV = (unit < 16);
        const int row = b * 16 + (isV ? unit : unit - 16);
        const float* wrow = (isV ? w_hh0 : w_hh1) + (size_t)row * H;
        const float* hs = isV ? h0s : h1s;
        float acc = 0.f;
        #pragma unroll
        for (int k = 0; k < 4; k++) {
            const int c = k * 256 + lane * 4;
            const float4 wv = *(const float4*)(wrow + c);
            acc += wv.x * hs[c] + wv.y * hs[c + 1] + wv.z * hs[c + 2] + wv.w * hs[c + 3];
        }
        acc = wave_reduce_sum(acc);
        if (lane == 0) {
            if (isV) v0[row] = acc + b_ih0[row] + b_hh0[row];
            else     u1[row] = acc + b_ih1[row] + b_hh1[row];
        }
    }
    if (b == 0) {
        c0[t]  = ctx[t];
        c1[t]  = ctx[H + t];
        h1g[t] = ctx[H + t];
        if (t < NB) keys[t] = 0ull;
        if (t == 0) {
            const unsigned int y0 = (unsigned int)y[0];
            // +inf value bits -> guaranteed winner; index = y[0]
            keys[0] = ((unsigned long long)0x7F800000u << 32) | (0xFFFFFFFFu - y0);
        }
    }
}

// ---------------------------------------------------------------------------
// K_A: argmax finalize (redundant), cell0 (redundant), w_ih1@h0 + cell1
//      (distributed, 4 h1 elems/block), w_hh0@h0 -> v0_out (next step)
// ---------------------------------------------------------------------------
__global__ __launch_bounds__(NT) void lstm_kernel(
    const float* __restrict__ w_ih0, const float* __restrict__ w_ih1,
    const float* __restrict__ w_hh0,
    const float* __restrict__ b_ih0, const float* __restrict__ b_hh0,
    const float* __restrict__ v0_in, float* __restrict__ v0_out,
    const float* __restrict__ u1,
    const float* __restrict__ c0_in, float* __restrict__ c0_out,
    float* __restrict__ c1, float* __restrict__ h1g,
    const unsigned long long* __restrict__ keys)
{
    __shared__ float h0s[H];
    __shared__ float g1s[16];
    __shared__ unsigned long long kred[NB];
    __shared__ float tok_s;
    const int b = blockIdx.x, t = threadIdx.x;

    // 1. finalize argmax from per-block keys (redundant in every block)
    if (t < NB) kred[t] = keys[t];
    __syncthreads();
    for (int s = NB / 2; s > 0; s >>= 1) {
        if (t < s) {
            const unsigned long long a = kred[t], c = kred[t + s];
            kred[t] = (a > c) ? a : c;
        }
        __syncthreads();
    }
    if (t == 0)
        tok_s = (float)(unsigned int)(0xFFFFFFFFu -
                 (unsigned int)(kred[0] & 0xFFFFFFFFull));
    __syncthreads();
    const float tok = tok_s;

    // 2. cell0 redundant: thread t = element j
    {
        const int j = t;
        const float gi = v0_in[j]         + tok * w_ih0[j];
        const float gf = v0_in[H + j]     + tok * w_ih0[H + j];
        const float gg = v0_in[2 * H + j] + tok * w_ih0[2 * H + j];
        const float go = v0_in[3 * H + j] + tok * w_ih0[3 * H + j];
        const float i_ = sigmoidf_(gi);
        const float f_ = sigmoidf_(gf);
        const float g_ = tanhf(gg);
        const float o_ = sigmoidf_(go);
        const float cn = f_ * c0_in[j] + i_ * g_;
        if (b == 0) c0_out[j] = cn;
        h0s[j] = o_ * tanhf(cn);
    }
    __syncthreads();

    // 3. 32 row-dots: units 0..15 -> g1 rows (w_ih1), 16..31 -> v0_out rows (w_hh0)
    const int wave = t >> 6, lane = t & 63;
    for (int unit = wave; unit < 32; unit += 16) {
        const bool isG1 = (unit < 16);
        const int sub = isG1 ? unit : unit - 16;   // sub = gate*4 + jj
        const int gate = sub >> 2, jj = sub & 3;
        const int row = gate * H + b * 4 + jj;
        const float* wrow = (isG1 ? w_ih1 : w_hh0) + (size_t)row * H;
        float acc = 0.f;
        #pragma unroll
        for (int k = 0; k < 4; k++) {
            const int c = k * 256 + lane * 4;
            const float4 wv = *(const float4*)(wrow + c);
            acc += wv.x * h0s[c] + wv.y * h0s[c + 1] + wv.z * h0s[c + 2] + wv.w * h0s[c + 3];
        }
        acc = wave_reduce_sum(acc);
        if (lane == 0) {
            if (isG1) g1s[sub]   = acc + u1[row];
            else      v0_out[row] = acc + b_ih0[row] + b_hh0[row];
        }
    }
    __syncthreads();

    // 4. cell1 for this block's 4 elements
    if (t < 4) {
        const int j = b * 4 + t;
        const float i_ = sigmoidf_(g1s[0 * 4 + t]);
        const float f_ = sigmoidf_(g1s[1 * 4 + t]);
        const float g_ = tanhf(g1s[2 * 4 + t]);
        const float o_ = sigmoidf_(g1s[3 * 4 + t]);
        const float cn = f_ * c1[j] + i_ * g_;
        c1[j] = cn;
        h1g[j] = o_ * tanhf(cn);
    }
}

// ---------------------------------------------------------------------------
// K_B: FC (125 rows/block) + relu + out write + per-block argmax key;
//      w_hh1@h1 -> u1 (next step)
// ---------------------------------------------------------------------------
__global__ __launch_bounds__(NT) void fc_kernel(
    const float* __restrict__ w_fc, const float* __restrict__ b_fc,
    const float* __restrict__ w_hh1, const float* __restrict__ b_ih1,
    const float* __restrict__ b_hh1,
    const float* __restrict__ h1g, float* __restrict__ u1,
    unsigned long long* __restrict__ keys,
    float* __restrict__ out_row)
{
    __shared__ float h1s[H];
    __shared__ unsigned long long wkey[16];
    const int b = blockIdx.x, t = threadIdx.x;
    h1s[t] = h1g[t];
    __syncthreads();

    const int wave = t >> 6, lane = t & 63;
    unsigned long long bestKey = 0ull;

    for (int i = 0; i < 8; i++) {
        const int rl = i * 16 + wave;
        if (rl >= RPB) break;
        const int row = b * RPB + rl;
        const float* wrow = w_fc + (size_t)row * H;
        float acc = 0.f;
        #pragma unroll
        for (int k = 0; k < 4; k++) {
            const int c = k * 256 + lane * 4;
            const float4 wv = *(const float4*)(wrow + c);
            acc += wv.x * h1s[c] + wv.y * h1s[c + 1] + wv.z * h1s[c + 2] + wv.w * h1s[c + 3];
        }
        acc = wave_reduce_sum(acc);
        if (lane == 0) {
            float p = acc + b_fc[row];
            p = p > 0.f ? p : 0.f;
            out_row[row] = p;
            const unsigned long long key =
                ((unsigned long long)__float_as_uint(p) << 32) |
                (0xFFFFFFFFu - (unsigned int)row);
            if (key > bestKey) bestKey = key;
        }
    }

    // u1 rows for next step: wave = sub = gate*4 + jj
    {
        const int gate = wave >> 2, jj = wave & 3;
        const int row = gate * H + b * 4 + jj;
        const float* wrow = w_hh1 + (size_t)row * H;
        float acc = 0.f;
        #pragma unroll
        for (int k = 0; k < 4; k++) {
            const int c = k * 256 + lane * 4;
            const float4 wv = *(const float4*)(wrow + c);
            acc += wv.x * h1s[c] + wv.y * h1s[c + 1] + wv.z * h1s[c + 2] + wv.w * h1s[c + 3];
        }
        acc = wave_reduce_sum(acc);
        if (lane == 0) u1[row] = acc + b_ih1[row] + b_hh1[row];
    }

    if (lane == 0) wkey[wave] = bestKey;
    __syncthreads();
    if (t == 0) {
        unsigned long long k = wkey[0];
        #pragma unroll
        for (int i = 1; i < 16; i++) k = (k > wkey[i]) ? k : wkey[i];
        keys[b] = k;
    }
}

// ---------------------------------------------------------------------------
// Host launcher
// ---------------------------------------------------------------------------
extern "C" void kernel_launch(void* const* d_in, const int* in_sizes, int n_in,
                              void* d_out, int out_size, void* d_ws, size_t ws_size,
                              hipStream_t stream)
{
    const int*   y     = (const int*)  d_in[0];
    const float* ctx   = (const float*)d_in[1];
    const float* w_ih0 = (const float*)d_in[2];
    const float* w_hh0 = (const float*)d_in[3];
    const float* b_ih0 = (const float*)d_in[4];
    const float* b_hh0 = (const float*)d_in[5];
    const float* w_ih1 = (const float*)d_in[6];
    const float* w_hh1 = (const float*)d_in[7];
    const float* b_ih1 = (const float*)d_in[8];
    const float* b_hh1 = (const float*)d_in[9];
    const float* w_fc  = (const float*)d_in[10];
    const float* b_fc  = (const float*)d_in[11];
    float* out = (float*)d_out;

    char* ws = (char*)d_ws;
    float* v0  = (float*)(ws + 0);        // [2][4096]
    float* u1  = (float*)(ws + 32768);    // [4096]
    float* c0  = (float*)(ws + 49152);    // [2][1024]
    float* c1  = (float*)(ws + 57344);    // [1024]
    float* h1g = (float*)(ws + 61440);    // [1024]
    unsigned long long* keys = (unsigned long long*)(ws + 65536); // [256]

    // out row 0 is defined as zeros
    hipMemsetAsync(d_out, 0, (size_t)V * sizeof(float), stream);

    init_kernel<<<NB, NT, 0, stream>>>(y, ctx, w_hh0, b_ih0, b_hh0,
                                       w_hh1, b_ih1, b_hh1,
                                       v0, u1, c0, c1, h1g, keys);

    for (int t = 1; t < L; t++) {
        const float* v0i = v0 + ((t - 1) & 1) * G4;
        float*       v0o = v0 + (t & 1) * G4;
        const float* c0i = c0 + ((t - 1) & 1) * H;
        float*       c0o = c0 + (t & 1) * H;
        lstm_kernel<<<NB, NT, 0, stream>>>(w_ih0, w_ih1, w_hh0, b_ih0, b_hh0,
                                           v0i, v0o, u1, c0i, c0o, c1, h1g, keys);
        fc_kernel<<<NB, NT, 0, stream>>>(w_fc, b_fc, w_hh1, b_ih1, b_hh1,
                                         h1g, u1, keys, out + (size_t)t * V);
    }
}